// Round 18
// baseline (73.401 us; speedup 1.0000x reference)
//
#include <hip/hip_runtime.h>

// sPLL — 2 cells/thread ILP + float2 stores + 2 parity roles:
//   * each thread simulates cells n=2i and 2i+1 (two INDEPENDENT chains
//     interleave in the pipe => dependency bubbles filled in-wave)
//   * paired spikes stored as one float2 (half the store instructions)
//   * block covers 2 trials (threads 0-127 -> b0, 128-255 -> b1)
//   * 2 roles by t-parity (both compute all 500 steps, store t%2==role)
//   * grid = 256 blocks = 1/CU.  do_step byte-identical to R15/R17 (PASS).
static constexpr int T  = 500;
static constexpr int BS = 256;
static constexpr int N  = 256;
static constexpr int U  = 10;
static constexpr int LDP = 504;            // padded row (8B-aligned rows)

#define FPBAR(x) asm("" : "+v"(x))

struct Cell { float Vl, Il, crl, Vt, itrg, ifac, crt; bool sp; };

__device__ __forceinline__ void do_step(float x, float steady, Cell& c,
                                        float& sl_out, float& st_out)
{
    const float RC = 999.99993896484375f;   // f32(1/f32(0.001))
    // ---- LIF ----
    float u0 = c.Il * 0.8f;                      FPBAR(u0);
    float u1 = c.sp ? 1e-3f : 0.0f;
    c.Il = u0 + u1;                              FPBAR(c.Il);
    float u3 = -c.Vl * 100.0f;                   FPBAR(u3);
    float u4 = c.Il + steady;                    FPBAR(u4);
    float u6 = __builtin_fmaf(u4, RC, u3);       FPBAR(u6);
    c.Vl = __builtin_fmaf(1e-3f, u6, c.Vl);      FPBAR(c.Vl);
    bool  bl  = c.Vl > 1.0f;
    float crm = c.crl - 1.0f;
    bool  rg  = crm <= 0.0f;
    c.crl = bl ? 2.0f : crm;
    c.Vl  = (!bl && rg) ? c.Vl : 0.0f;
    sl_out = bl ? 1.0f : 0.0f;
    // ---- TDE ----
    float u13 = bl ? 1.0f : c.ifac;
    c.ifac = u13 * 0.8f;                         FPBAR(c.ifac);
    float w0 = c.itrg * 0.9f;                    FPBAR(w0);
    float df  = c.ifac + c.ifac;
    float dfx = x * df;                          FPBAR(dfx);
    bool  m1  = c.ifac > 0.1f;
    float pulse = m1 ? dfx : 0.0f;
    c.itrg = w0 + pulse;                         FPBAR(c.itrg);
    float u18 = -c.Vt * 100.0f;                  FPBAR(u18);
    float u20 = __builtin_fmaf(c.itrg, RC, u18); FPBAR(u20);
    c.Vt = __builtin_fmaf(1e-3f, u20, c.Vt);     FPBAR(c.Vt);
    bool  bt  = c.Vt > 1.0f;
    float ctm = c.crt - 1.0f;
    bool  rg2 = ctm <= 0.0f;
    c.crt = bt ? 2.0f : ctm;
    c.Vt  = (!bt && rg2) ? c.Vt : 0.0f;
    st_out = bt ? 1.0f : 0.0f;
    c.sp = bt;
}

template <int PAR>
__device__ __forceinline__ void run_group(const float* sxp,
                                          float st0, float st1,
                                          Cell& c0, Cell& c1,
                                          float2*& q0, float2*& q1)
{
    const size_t step2 = (size_t)BS * N / 2;   // float2 units per timestep
    const float2 x01 = *reinterpret_cast<const float2*>(sxp + 0);
    const float2 x23 = *reinterpret_cast<const float2*>(sxp + 2);
    const float2 x45 = *reinterpret_cast<const float2*>(sxp + 4);
    const float2 x67 = *reinterpret_cast<const float2*>(sxp + 6);
    const float2 x89 = *reinterpret_cast<const float2*>(sxp + 8);
    const float xs[U] = {x01.x, x01.y, x23.x, x23.y, x45.x,
                         x45.y, x67.x, x67.y, x89.x, x89.y};
#pragma unroll
    for (int j = 0; j < U; ++j) {
        float sla, sta, slb, stb;
        do_step(xs[j], st0, c0, sla, sta);
        do_step(xs[j], st1, c1, slb, stb);
        if ((j & 1) == PAR) {
            q0[(size_t)j * step2] = make_float2(sla, slb);
            q1[(size_t)j * step2] = make_float2(sta, stb);
        }
    }
    q0 += (size_t)U * step2;
    q1 += (size_t)U * step2;
}

__global__ __launch_bounds__(256, 1) void spll_kernel(
    const float* __restrict__ inp,      // (T, BS)
    const float* __restrict__ current,  // (N,)
    float* __restrict__ out)            // (2, T, BS, N)
{
#pragma clang fp contract(off)
    const int B    = blockIdx.x & 127;       // trial pair
    const int role = blockIdx.x >> 7;        // 0: even t, 1: odd t
    const int half = threadIdx.x >> 7;       // 0 -> b0, 1 -> b1
    const int i    = threadIdx.x & 127;      // cell pair index
    const int b    = 2 * B + half;
    const int n0   = 2 * i;

    __shared__ __align__(16) float s_inp[2][LDP];
    for (int t = threadIdx.x; t < T; t += blockDim.x) {
        const float2 xv = *reinterpret_cast<const float2*>(&inp[t * BS + 2 * B]);
        s_inp[0][t] = xv.x;
        s_inp[1][t] = xv.y;
    }
    __syncthreads();

    const float2 stv = *reinterpret_cast<const float2*>(&current[n0]);
    const float st0 = stv.x, st1 = stv.y;

    Cell c0 = {1.0f, 0.0f, 0.0f, 0.0f, 0.0f, 0.0f, 0.0f, false};
    Cell c1 = {1.0f, 0.0f, 0.0f, 0.0f, 0.0f, 0.0f, 0.0f, false};

    float2* q0 = reinterpret_cast<float2*>(out) + ((size_t)b * N + n0) / 2;
    float2* q1 = q0 + (size_t)T * BS * N / 2;
    const float* srow = s_inp[half];

    if (role == 0) {
        for (int g = 0; g < T / U; ++g)
            run_group<0>(&srow[g * U], st0, st1, c0, c1, q0, q1);
    } else {
        for (int g = 0; g < T / U; ++g)
            run_group<1>(&srow[g * U], st0, st1, c0, c1, q0, q1);
    }
}

extern "C" void kernel_launch(void* const* d_in, const int* in_sizes, int n_in,
                              void* d_out, int out_size, void* d_ws, size_t ws_size,
                              hipStream_t stream) {
    const float* a0 = (const float*)d_in[0];
    const float* a1 = (const float*)d_in[1];
    const float* inp = a0;
    const float* cur = a1;
    if (n_in >= 2 && in_sizes[0] == N && in_sizes[1] == T * BS) { inp = a1; cur = a0; }
    float* out = (float*)d_out;
    spll_kernel<<<dim3(2 * 128), dim3(256), 0, stream>>>(inp, cur, out);
}

// Round 19
// 70.469 us; speedup vs baseline: 1.0416x; 1.0416x over previous
//
#include <hip/hip_runtime.h>

// sPLL — 3-role group-parity split (R = 3 contexts/SIMD):
//   * 768 blocks (3/CU => 3 waves/SIMD). All roles compute all 500 steps
//     from the same init (bitwise-identical); role r stores groups with
//     g%3 == r (17/17/16 groups, symmetric finish, continuous store stream).
//   * do_step = R15/R17-verified step + R16-verified wave-uniform x==0
//     scalar branch (x is block-uniform, P(x!=0)=0.1 => ~4 VALU/step saved).
static constexpr int T  = 500;
static constexpr int BS = 256;
static constexpr int N  = 256;
static constexpr int U  = 10;
static constexpr int R  = 3;

#define FPBAR(x) asm("" : "+v"(x))

struct Cell { float Vl, Il, crl, Vt, itrg, ifac, crt; bool sp; };

__device__ __forceinline__ void do_step(float x, unsigned xu, float steady,
                                        Cell& c, float& sl_out, float& st_out)
{
    const float RC = 999.99993896484375f;   // f32(1/f32(0.001))
    // ---- LIF ----
    float u0 = c.Il * 0.8f;                      FPBAR(u0);
    float u1 = c.sp ? 1e-3f : 0.0f;                         // == 1e-3f*spk
    c.Il = u0 + u1;                              FPBAR(c.Il);
    float u3 = -c.Vl * 100.0f;                   FPBAR(u3);
    float u4 = c.Il + steady;                    FPBAR(u4);
    float u6 = __builtin_fmaf(u4, RC, u3);       FPBAR(u6);
    c.Vl = __builtin_fmaf(1e-3f, u6, c.Vl);      FPBAR(c.Vl);
    bool  bl  = c.Vl > 1.0f;
    float crm = c.crl - 1.0f;                               // exact small ints
    bool  rg  = crm <= 0.0f;
    c.crl = bl ? 2.0f : crm;
    c.Vl  = (!bl && rg) ? c.Vl : 0.0f;                      // verified exact
    sl_out = bl ? 1.0f : 0.0f;
    // ---- TDE ----
    float u13 = bl ? 1.0f : c.ifac;                         // == spk + ifac*ns
    c.ifac = u13 * 0.8f;                         FPBAR(c.ifac);
    float w0 = c.itrg * 0.9f;                    FPBAR(w0);
    if (xu != 0u) {                              // x == 1.0f exactly (uniform)
        float df    = c.ifac + c.ifac;                      // exact 2x
        bool  m1    = c.ifac > 0.1f;
        float pulse = m1 ? df : 0.0f;                       // == (x*2)*ifac*m1
        float itn   = w0 + pulse;                FPBAR(itn);
        c.itrg = itn;
    } else {
        c.itrg = w0;                             // w0 + +0 == w0 (verified R16)
    }
    float u18 = -c.Vt * 100.0f;                  FPBAR(u18);
    float u20 = __builtin_fmaf(c.itrg, RC, u18); FPBAR(u20);
    c.Vt = __builtin_fmaf(1e-3f, u20, c.Vt);     FPBAR(c.Vt);
    bool  bt  = c.Vt > 1.0f;
    float ctm = c.crt - 1.0f;
    bool  rg2 = ctm <= 0.0f;
    c.crt = bt ? 2.0f : ctm;
    c.Vt  = (!bt && rg2) ? c.Vt : 0.0f;
    st_out = bt ? 1.0f : 0.0f;
    c.sp = bt;
}

template <bool STORE>
__device__ __forceinline__ void run_group(const float* sxp, float steady, Cell& c,
                                          float*& p0, float*& p1)
{
    const size_t step = (size_t)BS * N;
    const float2 x01 = *reinterpret_cast<const float2*>(sxp + 0);
    const float2 x23 = *reinterpret_cast<const float2*>(sxp + 2);
    const float2 x45 = *reinterpret_cast<const float2*>(sxp + 4);
    const float2 x67 = *reinterpret_cast<const float2*>(sxp + 6);
    const float2 x89 = *reinterpret_cast<const float2*>(sxp + 8);
    const float xs[U] = {x01.x, x01.y, x23.x, x23.y, x45.x,
                         x45.y, x67.x, x67.y, x89.x, x89.y};
    float sl, st;
#pragma unroll
    for (int j = 0; j < U; ++j) {
        unsigned xu = __builtin_amdgcn_readfirstlane(__float_as_uint(xs[j]));
        do_step(xs[j], xu, steady, c, sl, st);
        if (STORE) {
            p0[(size_t)j * step] = sl;
            p1[(size_t)j * step] = st;
        }
    }
    p0 += (size_t)U * step;
    p1 += (size_t)U * step;
}

__global__ __launch_bounds__(256, 3) void spll_kernel(
    const float* __restrict__ inp,      // (T, BS)
    const float* __restrict__ current,  // (N,)
    float* __restrict__ out)            // (2, T, BS, N)
{
#pragma clang fp contract(off)
    const int b    = blockIdx.x & (BS - 1);
    const int role = blockIdx.x >> 8;        // 0..2; stores groups g%3==role
    const int n    = threadIdx.x;

    __shared__ __align__(16) float s_inp[T];
    for (int i = threadIdx.x; i < T; i += blockDim.x)
        s_inp[i] = inp[i * BS + b];
    __syncthreads();

    const float steady = current[n];
    Cell c = {1.0f, 0.0f, 0.0f, 0.0f, 0.0f, 0.0f, 0.0f, false};

    float* p0 = out + (size_t)b * N + n;
    float* p1 = p0 + (size_t)T * BS * N;

    int phase = role;                         // store when phase == 0
    for (int g = 0; g < T / U; ++g) {
        if (phase == 0)
            run_group<true>(&s_inp[g * U], steady, c, p0, p1);
        else
            run_group<false>(&s_inp[g * U], steady, c, p0, p1);
        phase = (phase == 2) ? 0 : (phase + 1);
    }
}

extern "C" void kernel_launch(void* const* d_in, const int* in_sizes, int n_in,
                              void* d_out, int out_size, void* d_ws, size_t ws_size,
                              hipStream_t stream) {
    const float* a0 = (const float*)d_in[0];
    const float* a1 = (const float*)d_in[1];
    const float* inp = a0;
    const float* cur = a1;
    if (n_in >= 2 && in_sizes[0] == N && in_sizes[1] == T * BS) { inp = a1; cur = a0; }
    float* out = (float*)d_out;
    spll_kernel<<<dim3(R * BS), dim3(N), 0, stream>>>(inp, cur, out);
}

// Round 20
// 60.993 us; speedup vs baseline: 1.2034x; 1.1554x over previous
//
#include <hip/hip_runtime.h>

// sPLL — R=2 parity roles + LDS-decoupled burst stores:
//   512 blocks (2/CU); both roles compute all 500 steps (bitwise-identical,
//   R17-verified step); role r handles groups g%2==r:
//     compute group -> spikes into LDS buffer (ds_write_b32)
//     lgkmcnt-barrier -> burst store: 5x (ds_read_b128 -> store_dwordx4)
//     lgkmcnt-barrier (buffer free; global stores stay in flight)
//   Store sources come from LDS, not the recurrence chain => HBM write
//   backpressure throttles only store phases, never compute. Raw s_barrier
//   + manual lgkmcnt(0) avoids __syncthreads' vmcnt(0) full drain.
static constexpr int T  = 500;
static constexpr int BS = 256;
static constexpr int N  = 256;
static constexpr int U  = 10;          // group size; 50 groups

#define FPBAR(x) asm("" : "+v"(x))
#define LBAR()                                            \
    do {                                                  \
        asm volatile("s_waitcnt lgkmcnt(0)" ::: "memory");\
        __builtin_amdgcn_s_barrier();                     \
        __builtin_amdgcn_sched_barrier(0);                \
    } while (0)

struct Cell { float Vl, Il, crl, Vt, itrg, ifac, crt; bool sp; };

__device__ __forceinline__ void do_step(float x, float steady, Cell& c,
                                        float& sl_out, float& st_out)
{
    const float RC = 999.99993896484375f;   // f32(1/f32(0.001))
    // ---- LIF ----
    float u0 = c.Il * 0.8f;                      FPBAR(u0);
    float u1 = c.sp ? 1e-3f : 0.0f;                         // == 1e-3f*spk
    c.Il = u0 + u1;                              FPBAR(c.Il);
    float u3 = -c.Vl * 100.0f;                   FPBAR(u3);
    float u4 = c.Il + steady;                    FPBAR(u4);
    float u6 = __builtin_fmaf(u4, RC, u3);       FPBAR(u6);
    c.Vl = __builtin_fmaf(1e-3f, u6, c.Vl);      FPBAR(c.Vl);
    bool  bl  = c.Vl > 1.0f;
    float crm = c.crl - 1.0f;
    bool  rg  = crm <= 0.0f;
    c.crl = bl ? 2.0f : crm;
    c.Vl  = (!bl && rg) ? c.Vl : 0.0f;
    sl_out = bl ? 1.0f : 0.0f;
    // ---- TDE ----
    float u13 = bl ? 1.0f : c.ifac;
    c.ifac = u13 * 0.8f;                         FPBAR(c.ifac);
    float w0 = c.itrg * 0.9f;                    FPBAR(w0);
    float df  = c.ifac + c.ifac;
    float dfx = x * df;                          FPBAR(dfx);
    bool  m1  = c.ifac > 0.1f;
    float pulse = m1 ? dfx : 0.0f;
    c.itrg = w0 + pulse;                         FPBAR(c.itrg);
    float u18 = -c.Vt * 100.0f;                  FPBAR(u18);
    float u20 = __builtin_fmaf(c.itrg, RC, u18); FPBAR(u20);
    c.Vt = __builtin_fmaf(1e-3f, u20, c.Vt);     FPBAR(c.Vt);
    bool  bt  = c.Vt > 1.0f;
    float ctm = c.crt - 1.0f;
    bool  rg2 = ctm <= 0.0f;
    c.crt = bt ? 2.0f : ctm;
    c.Vt  = (!bt && rg2) ? c.Vt : 0.0f;
    st_out = bt ? 1.0f : 0.0f;
    c.sp = bt;
}

__global__ __launch_bounds__(256, 2) void spll_kernel(
    const float* __restrict__ inp,      // (T, BS)
    const float* __restrict__ current,  // (N,)
    float* __restrict__ out)            // (2, T, BS, N)
{
#pragma clang fp contract(off)
    const int b    = blockIdx.x & (BS - 1);
    const int role = blockIdx.x >> 8;        // stores groups g%2==role
    const int n    = threadIdx.x;

    __shared__ __align__(16) float s_inp[512];
    __shared__ __align__(16) float s_spk[U * 2 * N];   // 20 KB: [j][s][n]
    for (int i = threadIdx.x; i < T; i += blockDim.x)
        s_inp[i] = inp[i * BS + b];
    __syncthreads();

    const float steady = current[n];
    Cell c = {1.0f, 0.0f, 0.0f, 0.0f, 0.0f, 0.0f, 0.0f, false};
    const size_t step = (size_t)BS * N;      // 65536

    for (int g = 0; g < T / U; ++g) {
        const float* sxp = &s_inp[g * U];
        const float2 x01 = *reinterpret_cast<const float2*>(sxp + 0);
        const float2 x23 = *reinterpret_cast<const float2*>(sxp + 2);
        const float2 x45 = *reinterpret_cast<const float2*>(sxp + 4);
        const float2 x67 = *reinterpret_cast<const float2*>(sxp + 6);
        const float2 x89 = *reinterpret_cast<const float2*>(sxp + 8);
        const float xs[U] = {x01.x, x01.y, x23.x, x23.y, x45.x,
                             x45.y, x67.x, x67.y, x89.x, x89.y};
        float sl, st;

        if ((g & 1) == role) {
#pragma unroll
            for (int j = 0; j < U; ++j) {
                do_step(xs[j], steady, c, sl, st);
                s_spk[j * (2 * N) + n]     = sl;
                s_spk[j * (2 * N) + N + n] = st;
            }
            LBAR();                           // all spike writes visible
#pragma unroll
            for (int k = 0; k < 5; ++k) {     // 5 x 1024 floats
                const int f0 = k * 1024 + threadIdx.x * 4;
                const int j  = f0 >> 9;
                const int s  = (f0 >> 8) & 1;
                const int n0 = f0 & (N - 1);
                const float4 v = *reinterpret_cast<const float4*>(&s_spk[f0]);
                float* dst = out + ((size_t)s * T + (size_t)(g * U + j)) * step
                                 + (size_t)b * N + n0;
                *reinterpret_cast<float4*>(dst) = v;
            }
            LBAR();                           // LDS reads done; buffer free
        } else {
#pragma unroll
            for (int j = 0; j < U; ++j)
                do_step(xs[j], steady, c, sl, st);
        }
    }
}

extern "C" void kernel_launch(void* const* d_in, const int* in_sizes, int n_in,
                              void* d_out, int out_size, void* d_ws, size_t ws_size,
                              hipStream_t stream) {
    const float* a0 = (const float*)d_in[0];
    const float* a1 = (const float*)d_in[1];
    const float* inp = a0;
    const float* cur = a1;
    if (n_in >= 2 && in_sizes[0] == N && in_sizes[1] == T * BS) { inp = a1; cur = a0; }
    float* out = (float*)d_out;
    spll_kernel<<<dim3(2 * BS), dim3(N), 0, stream>>>(inp, cur, out);
}